// Round 22
// baseline (193.870 us; speedup 1.0000x reference)
//
#include <hip/hip_runtime.h>
#include <hip/hip_bf16.h>
#include <hip/hip_cooperative_groups.h>

namespace cg = cooperative_groups;

typedef float float4a __attribute__((ext_vector_type(4), aligned(4)));
typedef float float2a __attribute__((ext_vector_type(2), aligned(4)));
typedef short bfrag   __attribute__((ext_vector_type(8)));   // 8 bf16 (MFMA A/B frag)
typedef float f32x4   __attribute__((ext_vector_type(4)));

// ---------------- dims ----------------
#define P1W_PAD 128            // p1 row stride (f32), cols 123..127 zero
#define APAD 56064             // A row stride (f32) = 219*256, elems 55815.. zero
#define KFC 55815
#define CHUNK 256
#define NCHUNK 219
#define NFC1 120

// ws byte offsets
#define oP1B   ((size_t)0)            // 24,182,784
#define oAB    ((size_t)24182784)     // 14,352,384
#define oPARTB ((size_t)38535168)     // 219*7680*4 = 6,727,680

// ================= fused persistent kernel: conv1 | conv2 | fc1_s1 | tail =================
// grid 256 x block 1024 (4 teams of 256); 98.3KB LDS -> 1 block/CU (co-resident)
__global__ __launch_bounds__(1024) void fused_all(
        const float* __restrict__ x,
        const float* __restrict__ c1w, const float* __restrict__ c1b,
        const float* __restrict__ c2w, const float* __restrict__ c2b,
        const float* __restrict__ W,   const float* __restrict__ fc1b,
        const float* __restrict__ fc2w, const float* __restrict__ fc2b,
        const float* __restrict__ centers,
        const float* __restrict__ w1, const float* __restrict__ b1,
        const float* __restrict__ w2, const float* __restrict__ b2,
        const float* __restrict__ w3, const float* __restrict__ b3,
        float* __restrict__ p1, float* __restrict__ A,
        float* __restrict__ part, float* __restrict__ out) {
    cg::grid_group gg = cg::this_grid();
    __shared__ float smem[4 * 6144];      // 98.3 KB: 4 teams x 6144 floats
    const int bid  = blockIdx.x;
    const int tid  = threadIdx.x;
    const int team = tid >> 8;            // 0..3
    const int lt   = tid & 255;           // local tid within team
    float* tsm = smem + team * 6144;

    // ============ phase 1: conv1 (r8 body; 1152 units = (18 G, 64 b), 2 rounds) ============
    for (int rnd = 0; rnd < 2; ++rnd) {
        const int u = rnd * 1024 + bid * 4 + team;
        const bool uok = (u < 1152);
        const int G = uok ? (u % 18) : 0;
        const int b = uok ? (u / 18) : 0;
        const int t = lt >> 5;
        const int s = lt & 31;
        const int r = 7 * G + t;
        const bool act = uok && (r < 124) && (s < 31);

        if (act) {
            float acc[6][4];
            #pragma unroll
            for (int c = 0; c < 6; ++c) {
                const float bz = c1b[c];
                #pragma unroll
                for (int j = 0; j < 4; ++j) acc[c][j] = bz;
            }
            for (int ic = 0; ic < 3; ++ic) {
                const float* xpl = x + (size_t)(b * 3 + ic) * 62500;
                #pragma unroll
                for (int ky = 0; ky < 5; ++ky) {
                    const int iy = 2 * r - 1 + ky;
                    if (iy < 0) continue;                   // top pad (bottom never hit)
                    const float* rp = xpl + iy * 250 + 8 * s;
                    float a[11];
                    a[0] = (s > 0) ? rp[-1] : 0.f;          // left pad
                    *(float4a*)&a[1] = *(const float4a*)rp;
                    *(float4a*)&a[5] = *(const float4a*)(rp + 4);
                    *(float2a*)&a[9] = *(const float2a*)(rp + 8);
                    const float* wb = c1w + ic * 25 + ky * 5;   // + c*75 + kx
                    #pragma unroll
                    for (int c = 0; c < 6; ++c) {
                        #pragma unroll
                        for (int kx = 0; kx < 5; ++kx) {
                            const float wv = wb[c * 75 + kx];
                            #pragma unroll
                            for (int j = 0; j < 4; ++j)
                                acc[c][j] = fmaf(a[2 * j + kx], wv, acc[c][j]);
                        }
                    }
                }
            }
            #pragma unroll
            for (int c = 0; c < 6; ++c)
                *(float4*)&tsm[(t * 6 + c) * 128 + 4 * s] = *(float4*)&acc[c][0];
        }
        __syncthreads();
        if (uok) {
            const int np = min(7, 123 - 7 * G);
            for (int idx = lt; idx < np * 768; idx += 256) {    // 768 = 6*128
                const int p   = idx / 768;
                const int rem = idx - p * 768;                  // NOT & 767 (768 != 2^n)
                const int c   = rem >> 7;
                const int pc  = rem & 127;
                float v = 0.f;
                if (pc < 123) {
                    const float* r0 = &tsm[((p    ) * 6 + c) * 128 + pc];
                    const float* r1 = &tsm[((p + 1) * 6 + c) * 128 + pc];
                    v = fmaxf(fmaxf(fmaxf(r0[0], r0[1]), fmaxf(r1[0], r1[1])), 0.f);
                }
                p1[((size_t)(b * 6 + c) * 123 + (7 * G + p)) * P1W_PAD + pc] = v;
            }
        }
        __syncthreads();
    }
    gg.sync();

    // ============ phase 2: conv2 v2 (960 units = (5 G, 64 b, 3 cg)) ============
    {
        const int u = bid * 4 + team;
        const bool uok = (u < 960);
        const int G  = uok ? (u % 5) : 0;
        const int b  = uok ? ((u / 5) % 64) : 0;
        const int cb = uok ? ((u / 320) * 5) : 0;
        const int t = lt >> 4;
        const int s = lt & 15;
        const int r = 15 * G + t;
        const bool act = uok && (r < 62);

        if (act) {
            float acc[5][4];
            #pragma unroll
            for (int c = 0; c < 5; ++c) {
                const float bz = c2b[cb + c];
                #pragma unroll
                for (int j = 0; j < 4; ++j) acc[c][j] = bz;
            }
            for (int ic = 0; ic < 6; ++ic) {
                const float* pl = p1 + (size_t)(b * 6 + ic) * 123 * P1W_PAD;
                #pragma unroll
                for (int ky = 0; ky < 3; ++ky) {
                    const int iy = 2 * r - 1 + ky;
                    if (iy < 0 || iy > 122) continue;
                    const float* rp = pl + iy * P1W_PAD + 8 * s;
                    float a[9];
                    a[0] = (s > 0) ? rp[-1] : 0.f;          // left pad (cols>=123 are 0)
                    *(float4a*)&a[1] = *(const float4a*)rp;
                    *(float4a*)&a[5] = *(const float4a*)(rp + 4);
                    const float* wb = c2w + ic * 9 + ky * 3;    // + (cb+c)*54 + kx
                    #pragma unroll
                    for (int c = 0; c < 5; ++c) {
                        #pragma unroll
                        for (int kx = 0; kx < 3; ++kx) {
                            const float wv = wb[(cb + c) * 54 + kx];
                            #pragma unroll
                            for (int j = 0; j < 4; ++j)
                                acc[c][j] = fmaf(a[2 * j + kx], wv, acc[c][j]);
                        }
                    }
                }
            }
            #pragma unroll
            for (int c = 0; c < 5; ++c)
                *(float4*)&tsm[(t * 5 + c) * 64 + 4 * s] = *(float4*)&acc[c][0];
        }
        __syncthreads();
        if (uok) {
            const int np = min(15, 61 - 15 * G);
            for (int idx = lt; idx < np * 305; idx += 256) {    // 305 = 5*61
                const int p   = idx / 305;
                const int rem = idx % 305;
                const int c   = rem / 61;
                const int pc  = rem % 61;
                const float* r0 = &tsm[((p    ) * 5 + c) * 64 + pc];
                const float* r1 = &tsm[((p + 1) * 5 + c) * 64 + pc];
                const float v = fmaxf(fmaxf(r0[0], r0[1]), fmaxf(r1[0], r1[1]));
                A[(size_t)b * APAD + (cb + c) * 3721 + (15 * G + p) * 61 + pc] = fmaxf(v, 0.f);
            }
            if (G == 0 && cb == 0)
                for (int i2 = lt; i2 < 249; i2 += 256)
                    A[(size_t)b * APAD + KFC + i2] = 0.f;
        }
        __syncthreads();
    }
    gg.sync();

    // ============ phase 3: fc1_s1 v5 (876 units = (219 cBlk, 4 nth); no barriers) ============
    {
        const int u = bid * 4 + team;
        if (u < 876) {
            const int cBlk = u % 219;
            const int nth  = u / 219;
            const int k0 = cBlk * CHUNK;
            const int lane  = lt & 63;
            const int mtile = lt >> 6;
            const int ocol  = lane & 15;
            const int kq    = lane >> 4;
            const int arow  = mtile * 16 + ocol;

            const float* ab = A + (size_t)arow * APAD + k0 + kq * 8;
            const float* wbp[2];
            #pragma unroll
            for (int ntl = 0; ntl < 2; ++ntl) {
                const int o = (nth * 2 + ntl) * 16 + ocol;
                wbp[ntl] = W + (size_t)min(o, NFC1 - 1) * KFC + k0 + kq * 8;
            }

            f32x4 acc[2];
            #pragma unroll
            for (int n = 0; n < 2; ++n) acc[n] = (f32x4){0.f, 0.f, 0.f, 0.f};

            const bool full = (cBlk != NCHUNK - 1);
            #pragma unroll 2
            for (int ks = 0; ks < 8; ++ks) {
                float af[8];
                *(float4a*)&af[0] = *(const float4a*)(ab + ks * 32);
                *(float4a*)&af[4] = *(const float4a*)(ab + ks * 32 + 4);
                bfrag ah, al;
                #pragma unroll
                for (int e = 0; e < 8; ++e) {
                    const unsigned uu = __float_as_uint(af[e]);
                    ah[e] = (short)(uu >> 16);
                    const float rres = af[e] - __uint_as_float(uu & 0xffff0000u);
                    al[e] = (short)(__float_as_uint(rres) >> 16);
                }
                #pragma unroll
                for (int ntl = 0; ntl < 2; ++ntl) {
                    float wf[8];
                    if (full) {
                        *(float4a*)&wf[0] = *(const float4a*)(wbp[ntl] + ks * 32);
                        *(float4a*)&wf[4] = *(const float4a*)(wbp[ntl] + ks * 32 + 4);
                    } else {
                        const int kg = k0 + ks * 32 + kq * 8;
                        #pragma unroll
                        for (int e = 0; e < 8; ++e)
                            wf[e] = (kg + e < KFC) ? wbp[ntl][ks * 32 + e] : 0.f;
                    }
                    bfrag wh, wl;
                    #pragma unroll
                    for (int e = 0; e < 8; ++e) {
                        const unsigned uu = __float_as_uint(wf[e]);
                        wh[e] = (short)(uu >> 16);
                        const float rres = wf[e] - __uint_as_float(uu & 0xffff0000u);
                        wl[e] = (short)(__float_as_uint(rres) >> 16);
                    }
                    acc[ntl] = __builtin_amdgcn_mfma_f32_16x16x32_bf16(ah, wh, acc[ntl], 0, 0, 0);
                    acc[ntl] = __builtin_amdgcn_mfma_f32_16x16x32_bf16(al, wh, acc[ntl], 0, 0, 0);
                    acc[ntl] = __builtin_amdgcn_mfma_f32_16x16x32_bf16(ah, wl, acc[ntl], 0, 0, 0);
                }
            }
            #pragma unroll
            for (int ntl = 0; ntl < 2; ++ntl) {
                const int o = (nth * 2 + ntl) * 16 + ocol;
                if (o < NFC1) {
                    #pragma unroll
                    for (int rr = 0; rr < 4; ++rr) {
                        const int brow = mtile * 16 + kq * 4 + rr;
                        part[((size_t)cBlk * 64 + brow) * NFC1 + o] = acc[ntl][rr];
                    }
                }
            }
        }
    }
    gg.sync();

    // ============ phase 4: tail v3 (blocks 0..63; full 1024 threads) ============
    if (bid >= 64) return;
    {
        const int b = bid;
        float* partial = smem;            // 960
        float* h    = smem + 960;         // 120
        float* feat = smem + 1080;        // 4
        float* bufA = smem + 1084;        // 64
        float* bufB = smem + 1148;        // 64

        if (tid < 960) {
            const int o = tid % 120;
            const int g = tid / 120;
            const int c0 = g * 27 + min(g, 3);
            const int n  = 27 + (g < 3 ? 1 : 0);
            float s0 = 0.f, s1v = 0.f, s2v = 0.f, s3v = 0.f;
            int c = c0;
            for (; c + 3 < c0 + n; c += 4) {
                s0  += part[((size_t)(c + 0) * 64 + b) * NFC1 + o];
                s1v += part[((size_t)(c + 1) * 64 + b) * NFC1 + o];
                s2v += part[((size_t)(c + 2) * 64 + b) * NFC1 + o];
                s3v += part[((size_t)(c + 3) * 64 + b) * NFC1 + o];
            }
            for (; c < c0 + n; ++c) s0 += part[((size_t)c * 64 + b) * NFC1 + o];
            partial[g * 120 + o] = (s0 + s1v) + (s2v + s3v);
        }
        __syncthreads();
        if (tid < 120) {
            float sv = fc1b[tid];
            #pragma unroll
            for (int g = 0; g < 8; ++g) sv += partial[g * 120 + tid];
            h[tid] = fmaxf(sv, 0.f);
        }
        __syncthreads();

        if (tid < 64) {
            const int j = tid >> 4, p = tid & 15;
            float sv = 0.f;
            for (int o = p; o < NFC1; o += 16) sv = fmaf(fc2w[j * NFC1 + o], h[o], sv);
            #pragma unroll
            for (int off = 8; off; off >>= 1) sv += __shfl_xor(sv, off, 16);
            if (p == 0) feat[j] = fmaxf(sv + fc2b[j], 0.f);
        }
        __syncthreads();

        if (tid < 64) {
            float prod = 1.f;
            #pragma unroll
            for (int i = 0; i < 4; ++i) prod *= cosf(0.5f * (feat[i] - centers[tid * 84 + i]));
            bufA[tid] = fabsf(prod);
        }
        __syncthreads();
        if (tid < 64) {
            float s1v = b1[tid];
            for (int jj = 0; jj < 64; ++jj) s1v = fmaf(w1[tid * 64 + jj], bufA[jj], s1v);
            bufB[tid] = fmaxf(s1v, 0.f);
        }
        __syncthreads();
        if (tid < 64) {
            float s2v = b2[tid];
            for (int jj = 0; jj < 64; ++jj) s2v = fmaf(w2[tid * 64 + jj], bufB[jj], s2v);
            bufA[tid] = fmaxf(s2v, 0.f);
        }
        __syncthreads();
        if (tid < 2) {
            float s3v = b3[tid];
            for (int jj = 0; jj < 64; ++jj) s3v = fmaf(w3[tid * 64 + jj], bufA[jj], s3v);
            const float other = __shfl_xor(s3v, 1, 2);
            const float m = fmaxf(s3v, other);
            const float e = expf(s3v - m), eo = expf(other - m);
            out[b * 2 + tid] = e / (e + eo);
        }
    }
}

// ---------------- launcher ----------------
extern "C" void kernel_launch(void* const* d_in, const int* in_sizes, int n_in,
                              void* d_out, int out_size, void* d_ws, size_t ws_size,
                              hipStream_t stream) {
    const float* x       = (const float*)d_in[0];
    const float* conv1_w = (const float*)d_in[1];
    const float* conv1_b = (const float*)d_in[2];
    const float* conv2_w = (const float*)d_in[3];
    const float* conv2_b = (const float*)d_in[4];
    const float* fc1_w   = (const float*)d_in[5];
    const float* fc1_b   = (const float*)d_in[6];
    const float* fc2_w   = (const float*)d_in[7];
    const float* fc2_b   = (const float*)d_in[8];
    const float* centers = (const float*)d_in[9];
    const float* cls_w1  = (const float*)d_in[10];
    const float* cls_b1  = (const float*)d_in[11];
    const float* cls_w2  = (const float*)d_in[12];
    const float* cls_b2  = (const float*)d_in[13];
    const float* cls_w3  = (const float*)d_in[14];
    const float* cls_b3  = (const float*)d_in[15];
    char* ws = (char*)d_ws;
    float* outp = (float*)d_out;

    float* p1    = (float*)(ws + oP1B);
    float* Abuf  = (float*)(ws + oAB);
    float* partb = (float*)(ws + oPARTB);

    void* args[] = {
        (void*)&x, (void*)&conv1_w, (void*)&conv1_b, (void*)&conv2_w, (void*)&conv2_b,
        (void*)&fc1_w, (void*)&fc1_b, (void*)&fc2_w, (void*)&fc2_b, (void*)&centers,
        (void*)&cls_w1, (void*)&cls_b1, (void*)&cls_w2, (void*)&cls_b2,
        (void*)&cls_w3, (void*)&cls_b3,
        (void*)&p1, (void*)&Abuf, (void*)&partb, (void*)&outp
    };
    hipLaunchCooperativeKernel((void*)fused_all, dim3(256), dim3(1024), args, 0, stream);
}

// Round 23
// 76.125 us; speedup vs baseline: 2.5467x; 2.5467x over previous
//
#include <hip/hip_runtime.h>
#include <hip/hip_bf16.h>

typedef float float4a __attribute__((ext_vector_type(4), aligned(4)));
typedef float float2a __attribute__((ext_vector_type(2), aligned(4)));
typedef short bfrag   __attribute__((ext_vector_type(8)));   // 8 bf16 (MFMA A/B frag)
typedef float f32x4   __attribute__((ext_vector_type(4)));

// ---------------- dims ----------------
#define P1W_PAD 128            // p1 row stride (f32), cols 123..127 zero
#define APAD 56064             // A row stride (f32) = 219*256, elems 55815.. zero
#define KFC 55815
#define CHUNK 256
#define NCHUNK 219
#define NFC1 120

// ws byte offsets
#define oP1B   ((size_t)0)            // 24,182,784
#define oAB    ((size_t)24182784)     // 14,352,384
#define oPARTB ((size_t)38535168)     // 219*7680*4 = 6,727,680

// ============ conv1 (3->6,k5,s2,p1)+ReLU+pool2s1 -> p1 f32[64][6][123][128] ============
// [r8-verbatim, measured 24.4 us — best of 4 variants; fetch-transaction-bound]
__global__ __launch_bounds__(256) void conv1_pool(const float* __restrict__ x,
        const float* __restrict__ w, const float* __restrict__ bias,
        float* __restrict__ p1) {
    __shared__ float ex[8 * 6 * 128];     // 24.6 KB
    const int tid = threadIdx.x;
    const int G = blockIdx.x;
    const int b = blockIdx.y;
    const int t = tid >> 5;
    const int s = tid & 31;
    const int r = 7 * G + t;
    const bool act = (r < 124) && (s < 31);

    if (act) {
        float acc[6][4];
        #pragma unroll
        for (int c = 0; c < 6; ++c) {
            const float bz = bias[c];
            #pragma unroll
            for (int j = 0; j < 4; ++j) acc[c][j] = bz;
        }
        for (int ic = 0; ic < 3; ++ic) {
            const float* xpl = x + (size_t)(b * 3 + ic) * 62500;
            #pragma unroll
            for (int ky = 0; ky < 5; ++ky) {
                const int iy = 2 * r - 1 + ky;
                if (iy < 0) continue;                       // top pad (bottom never hit)
                const float* rp = xpl + iy * 250 + 8 * s;
                float a[11];
                a[0] = (s > 0) ? rp[-1] : 0.f;              // left pad
                *(float4a*)&a[1] = *(const float4a*)rp;
                *(float4a*)&a[5] = *(const float4a*)(rp + 4);
                *(float2a*)&a[9] = *(const float2a*)(rp + 8);
                const float* wb = w + ic * 25 + ky * 5;     // + c*75 + kx (uniform s_loads)
                #pragma unroll
                for (int c = 0; c < 6; ++c) {
                    #pragma unroll
                    for (int kx = 0; kx < 5; ++kx) {
                        const float wv = wb[c * 75 + kx];
                        #pragma unroll
                        for (int j = 0; j < 4; ++j)
                            acc[c][j] = fmaf(a[2 * j + kx], wv, acc[c][j]);
                    }
                }
            }
        }
        #pragma unroll
        for (int c = 0; c < 6; ++c)
            *(float4*)&ex[(t * 6 + c) * 128 + 4 * s] = *(float4*)&acc[c][0];
    }
    __syncthreads();
    const int np = min(7, 123 - 7 * G);                     // pool rows this block
    for (int idx = tid; idx < np * 768; idx += 256) {       // 768 = 6*128
        const int p   = idx / 768;
        const int rem = idx - p * 768;                      // NOT & 767 (768 != 2^n)
        const int c   = rem >> 7;
        const int pc  = rem & 127;
        float v = 0.f;
        if (pc < 123) {
            const float* r0 = &ex[((p    ) * 6 + c) * 128 + pc];
            const float* r1 = &ex[((p + 1) * 6 + c) * 128 + pc];
            v = fmaxf(fmaxf(fmaxf(r0[0], r0[1]), fmaxf(r1[0], r1[1])), 0.f);
        }
        p1[((size_t)(b * 6 + c) * 123 + (7 * G + p)) * P1W_PAD + pc] = v;
    }
}

// ============ conv2 v2 (6->15,k3,s2,p1)+ReLU+pool2s1 -> A f32[64][56064] [r16-proven] ============
// grid (5, 64, 3): blockIdx.z = channel group of 5; block 256 = 16 rows x 16 strips
__global__ __launch_bounds__(256) void conv2_pool(const float* __restrict__ p1,
        const float* __restrict__ w, const float* __restrict__ bias,
        float* __restrict__ A) {
    __shared__ float ex[16 * 5 * 64];     // 20.5 KB
    const int tid = threadIdx.x;
    const int G = blockIdx.x;
    const int b = blockIdx.y;
    const int cb = blockIdx.z * 5;        // channel base
    const int t = tid >> 4;
    const int s = tid & 15;
    const int r = 15 * G + t;
    const bool act = (r < 62);

    if (act) {
        float acc[5][4];
        #pragma unroll
        for (int c = 0; c < 5; ++c) {
            const float bz = bias[cb + c];
            #pragma unroll
            for (int j = 0; j < 4; ++j) acc[c][j] = bz;
        }
        for (int ic = 0; ic < 6; ++ic) {
            const float* pl = p1 + (size_t)(b * 6 + ic) * 123 * P1W_PAD;
            #pragma unroll
            for (int ky = 0; ky < 3; ++ky) {
                const int iy = 2 * r - 1 + ky;
                if (iy < 0 || iy > 122) continue;
                const float* rp = pl + iy * P1W_PAD + 8 * s;
                float a[9];
                a[0] = (s > 0) ? rp[-1] : 0.f;              // left pad (cols>=123 are 0)
                *(float4a*)&a[1] = *(const float4a*)rp;
                *(float4a*)&a[5] = *(const float4a*)(rp + 4);
                const float* wb = w + ic * 9 + ky * 3;      // + (cb+c)*54 + kx (uniform)
                #pragma unroll
                for (int c = 0; c < 5; ++c) {
                    #pragma unroll
                    for (int kx = 0; kx < 3; ++kx) {
                        const float wv = wb[(cb + c) * 54 + kx];
                        #pragma unroll
                        for (int j = 0; j < 4; ++j)
                            acc[c][j] = fmaf(a[2 * j + kx], wv, acc[c][j]);
                    }
                }
            }
        }
        #pragma unroll
        for (int c = 0; c < 5; ++c)
            *(float4*)&ex[(t * 5 + c) * 64 + 4 * s] = *(float4*)&acc[c][0];
    }
    __syncthreads();
    const int np = min(15, 61 - 15 * G);
    for (int idx = tid; idx < np * 305; idx += 256) {       // 305 = 5*61 (true modulo)
        const int p   = idx / 305;
        const int rem = idx % 305;
        const int c   = rem / 61;
        const int pc  = rem % 61;
        const float* r0 = &ex[((p    ) * 5 + c) * 64 + pc];
        const float* r1 = &ex[((p + 1) * 5 + c) * 64 + pc];
        const float v = fmaxf(fmaxf(r0[0], r0[1]), fmaxf(r1[0], r1[1]));
        A[(size_t)b * APAD + (cb + c) * 3721 + (15 * G + p) * 61 + pc] = fmaxf(v, 0.f);
    }
    if (G == 0 && cb == 0)                                  // zero the K-pad tail (once)
        for (int i2 = tid; i2 < 249; i2 += 256)
            A[(size_t)b * APAD + KFC + i2] = 0.f;
}

// ============ fc1 split-K MFMA [r10-verbatim; measured 18.5 us across 5 variants] ============
// part[c][64 b][120 o]; grid (219,2); block 256 = 4 mtile waves; nth = N-half
__global__ __launch_bounds__(256) void fc1_s1(const float* __restrict__ A,
        const float* __restrict__ W, float* __restrict__ part) {
    const int cBlk = blockIdx.x;
    const int nth  = blockIdx.y;          // 0/1
    const int k0 = cBlk * CHUNK;
    const int tid = threadIdx.x;
    const int lane  = tid & 63;
    const int mtile = tid >> 6;           // 0..3
    const int ocol  = lane & 15;
    const int kq    = lane >> 4;          // 0..3 (k-quad within 32-wide MFMA K)
    const int arow  = mtile * 16 + ocol;

    const float* ab = A + (size_t)arow * APAD + k0 + kq * 8;
    const float* wb[4];
    #pragma unroll
    for (int ntl = 0; ntl < 4; ++ntl) {
        const int o = (nth * 4 + ntl) * 16 + ocol;
        wb[ntl] = W + (size_t)min(o, NFC1 - 1) * KFC + k0 + kq * 8;
    }

    f32x4 acc[4];
    #pragma unroll
    for (int n = 0; n < 4; ++n) acc[n] = (f32x4){0.f, 0.f, 0.f, 0.f};

    const bool full = (cBlk != NCHUNK - 1);
    #pragma unroll 2
    for (int ks = 0; ks < 8; ++ks) {
        float af[8];
        *(float4a*)&af[0] = *(const float4a*)(ab + ks * 32);
        *(float4a*)&af[4] = *(const float4a*)(ab + ks * 32 + 4);
        bfrag ah, al;
        #pragma unroll
        for (int e = 0; e < 8; ++e) {
            const unsigned u = __float_as_uint(af[e]);
            ah[e] = (short)(u >> 16);                            // hi = trunc-bf16
            const float rres = af[e] - __uint_as_float(u & 0xffff0000u);
            al[e] = (short)(__float_as_uint(rres) >> 16);        // lo = trunc-bf16(res)
        }
        #pragma unroll
        for (int ntl = 0; ntl < 4; ++ntl) {
            float wf[8];
            if (full) {
                *(float4a*)&wf[0] = *(const float4a*)(wb[ntl] + ks * 32);
                *(float4a*)&wf[4] = *(const float4a*)(wb[ntl] + ks * 32 + 4);
            } else {                                        // last chunk: guard OOB (W alloc end)
                const int kg = k0 + ks * 32 + kq * 8;
                #pragma unroll
                for (int e = 0; e < 8; ++e)
                    wf[e] = (kg + e < KFC) ? wb[ntl][ks * 32 + e] : 0.f;
            }
            bfrag wh, wl;
            #pragma unroll
            for (int e = 0; e < 8; ++e) {
                const unsigned u = __float_as_uint(wf[e]);
                wh[e] = (short)(u >> 16);
                const float rres = wf[e] - __uint_as_float(u & 0xffff0000u);
                wl[e] = (short)(__float_as_uint(rres) >> 16);
            }
            acc[ntl] = __builtin_amdgcn_mfma_f32_16x16x32_bf16(ah, wh, acc[ntl], 0, 0, 0);
            acc[ntl] = __builtin_amdgcn_mfma_f32_16x16x32_bf16(al, wh, acc[ntl], 0, 0, 0);
            acc[ntl] = __builtin_amdgcn_mfma_f32_16x16x32_bf16(ah, wl, acc[ntl], 0, 0, 0);
        }
    }
    #pragma unroll
    for (int ntl = 0; ntl < 4; ++ntl) {
        const int o = (nth * 4 + ntl) * 16 + ocol;
        if (o < NFC1) {
            #pragma unroll
            for (int rr = 0; rr < 4; ++rr) {
                const int brow = mtile * 16 + kq * 4 + rr;  // C/D: row=(l>>4)*4+reg, col=l&15
                part[((size_t)cBlk * 64 + brow) * NFC1 + o] = acc[ntl][rr];
            }
        }
    }
}

// ============ tail v3 [r19-proven]: parallel chunk-reduce + head; grid 64, block 1024 ============
__global__ __launch_bounds__(1024) void tail_k(const float* __restrict__ part,
        const float* __restrict__ fc1b,
        const float* __restrict__ fc2w, const float* __restrict__ fc2b,
        const float* __restrict__ centers,
        const float* __restrict__ w1, const float* __restrict__ b1,
        const float* __restrict__ w2, const float* __restrict__ b2,
        const float* __restrict__ w3, const float* __restrict__ b3,
        float* __restrict__ out) {
    const int b = blockIdx.x;
    const int tid = threadIdx.x;
    __shared__ float partial[960];
    __shared__ float h[120];
    __shared__ float feat[4];
    __shared__ float bufA[64];
    __shared__ float bufB[64];

    // phase A: 960 threads = 8 chunk-groups x 120 outputs (3x28 + 5x27), 4-deep ILP
    if (tid < 960) {
        const int o = tid % 120;
        const int g = tid / 120;
        const int c0 = g * 27 + min(g, 3);
        const int n  = 27 + (g < 3 ? 1 : 0);
        float s0 = 0.f, s1 = 0.f, s2 = 0.f, s3 = 0.f;
        int c = c0;
        for (; c + 3 < c0 + n; c += 4) {
            s0 += part[((size_t)(c + 0) * 64 + b) * NFC1 + o];
            s1 += part[((size_t)(c + 1) * 64 + b) * NFC1 + o];
            s2 += part[((size_t)(c + 2) * 64 + b) * NFC1 + o];
            s3 += part[((size_t)(c + 3) * 64 + b) * NFC1 + o];
        }
        for (; c < c0 + n; ++c) s0 += part[((size_t)c * 64 + b) * NFC1 + o];
        partial[g * 120 + o] = (s0 + s1) + (s2 + s3);
    }
    __syncthreads();
    if (tid < 120) {
        float sv = fc1b[tid];
        #pragma unroll
        for (int g = 0; g < 8; ++g) sv += partial[g * 120 + tid];
        h[tid] = fmaxf(sv, 0.f);
    }
    __syncthreads();

    if (tid < 64) {
        const int j = tid >> 4, p = tid & 15;
        float sv = 0.f;
        for (int o = p; o < NFC1; o += 16) sv = fmaf(fc2w[j * NFC1 + o], h[o], sv);
        #pragma unroll
        for (int off = 8; off; off >>= 1) sv += __shfl_xor(sv, off, 16);
        if (p == 0) feat[j] = fmaxf(sv + fc2b[j], 0.f);
    }
    __syncthreads();

    if (tid < 64) {
        float prod = 1.f;
        #pragma unroll
        for (int i = 0; i < 4; ++i) prod *= cosf(0.5f * (feat[i] - centers[tid * 84 + i]));
        bufA[tid] = fabsf(prod);
    }
    __syncthreads();
    if (tid < 64) {
        float s1v = b1[tid];
        for (int jj = 0; jj < 64; ++jj) s1v = fmaf(w1[tid * 64 + jj], bufA[jj], s1v);
        bufB[tid] = fmaxf(s1v, 0.f);
    }
    __syncthreads();
    if (tid < 64) {
        float s2v = b2[tid];
        for (int jj = 0; jj < 64; ++jj) s2v = fmaf(w2[tid * 64 + jj], bufB[jj], s2v);
        bufA[tid] = fmaxf(s2v, 0.f);
    }
    __syncthreads();
    if (tid < 2) {
        float s3v = b3[tid];
        for (int jj = 0; jj < 64; ++jj) s3v = fmaf(w3[tid * 64 + jj], bufA[jj], s3v);
        const float other = __shfl_xor(s3v, 1, 2);
        const float m = fmaxf(s3v, other);
        const float e = expf(s3v - m), eo = expf(other - m);
        out[b * 2 + tid] = e / (e + eo);
    }
}

// ---------------- launcher ----------------
extern "C" void kernel_launch(void* const* d_in, const int* in_sizes, int n_in,
                              void* d_out, int out_size, void* d_ws, size_t ws_size,
                              hipStream_t stream) {
    const float* x       = (const float*)d_in[0];
    const float* conv1_w = (const float*)d_in[1];
    const float* conv1_b = (const float*)d_in[2];
    const float* conv2_w = (const float*)d_in[3];
    const float* conv2_b = (const float*)d_in[4];
    const float* fc1_w   = (const float*)d_in[5];
    const float* fc1_b   = (const float*)d_in[6];
    const float* fc2_w   = (const float*)d_in[7];
    const float* fc2_b   = (const float*)d_in[8];
    const float* centers = (const float*)d_in[9];
    const float* cls_w1  = (const float*)d_in[10];
    const float* cls_b1  = (const float*)d_in[11];
    const float* cls_w2  = (const float*)d_in[12];
    const float* cls_b2  = (const float*)d_in[13];
    const float* cls_w3  = (const float*)d_in[14];
    const float* cls_b3  = (const float*)d_in[15];
    char* ws = (char*)d_ws;
    float* outp = (float*)d_out;

    float* p1    = (float*)(ws + oP1B);
    float* Abuf  = (float*)(ws + oAB);
    float* partb = (float*)(ws + oPARTB);

    hipLaunchKernelGGL(conv1_pool, dim3(18, 64), dim3(256), 0, stream, x, conv1_w, conv1_b, p1);
    hipLaunchKernelGGL(conv2_pool, dim3(5, 64, 3), dim3(256), 0, stream, p1, conv2_w, conv2_b, Abuf);
    hipLaunchKernelGGL(fc1_s1, dim3(NCHUNK, 2), dim3(256), 0, stream, Abuf, fc1_w, partb);
    hipLaunchKernelGGL(tail_k, dim3(64), dim3(1024), 0, stream,
                       partb, fc1_b, fc2_w, fc2_b, centers,
                       cls_w1, cls_b1, cls_w2, cls_b2, cls_w3, cls_b3, outp);
}